// Round 1
// baseline (2436.302 us; speedup 1.0000x reference)
//
#include <hip/hip_runtime.h>
#include <math.h>

constexpr int B = 8, NQ = 256, LT = 512, NV = 4096;
constexpr int D = 1024, H = 16, DFF = 2048, FTXT = 4096, HD = 64;

// ---------------------------------------------------------------------------
// GEMM: C[M,N] = op( A[M,K] (+A2) ) @ Bw[N,K]^T  (+bias) (+res) (relu?)
// 64x64 tile, BK=32, 256 threads, 4x4 micro-tile. Batched via blockIdx.z.
// LDS layout transposed: Ast[k][m], Bst[k][n], pad 68 (16B-aligned rows).
// ---------------------------------------------------------------------------
template<bool ADD2, bool BIAS, bool RELU, bool RES>
__global__ __launch_bounds__(256)
void gemm_abt(const float* __restrict__ A, const float* __restrict__ A2,
              const float* __restrict__ Bw, const float* __restrict__ bias,
              const float* __restrict__ res, float* __restrict__ C,
              int M, int N, int K,
              long long sA, long long sB, long long sC)
{
  __shared__ float Ast[32][68];
  __shared__ float Bst[32][68];
  const int bz = blockIdx.z;
  A  += (long long)bz * sA;
  Bw += (long long)bz * sB;
  C  += (long long)bz * sC;
  const float* A2p = ADD2 ? (A2 + (long long)bz * sA) : nullptr;
  const float* rp  = RES  ? (res + (long long)bz * sC) : nullptr;

  const int m0 = blockIdx.y * 64, n0 = blockIdx.x * 64;
  const int t  = threadIdx.x;
  const int tx = t & 15, ty = t >> 4;
  float acc[4][4] = {};

  for (int k0 = 0; k0 < K; k0 += 32) {
    #pragma unroll
    for (int p = 0; p < 2; ++p) {
      int lin = t + p * 256;          // 512 float4 slots = 64 rows x 8
      int row = lin >> 3;
      int c4  = lin & 7;
      float4 a4 = *reinterpret_cast<const float4*>(&A[(long long)(m0 + row) * K + k0 + c4 * 4]);
      if (ADD2) {
        float4 b4 = *reinterpret_cast<const float4*>(&A2p[(long long)(m0 + row) * K + k0 + c4 * 4]);
        a4.x += b4.x; a4.y += b4.y; a4.z += b4.z; a4.w += b4.w;
      }
      Ast[c4 * 4 + 0][row] = a4.x; Ast[c4 * 4 + 1][row] = a4.y;
      Ast[c4 * 4 + 2][row] = a4.z; Ast[c4 * 4 + 3][row] = a4.w;
    }
    #pragma unroll
    for (int p = 0; p < 2; ++p) {
      int lin = t + p * 256;
      int row = lin >> 3;
      int c4  = lin & 7;
      float4 b4 = *reinterpret_cast<const float4*>(&Bw[(long long)(n0 + row) * K + k0 + c4 * 4]);
      Bst[c4 * 4 + 0][row] = b4.x; Bst[c4 * 4 + 1][row] = b4.y;
      Bst[c4 * 4 + 2][row] = b4.z; Bst[c4 * 4 + 3][row] = b4.w;
    }
    __syncthreads();
    #pragma unroll
    for (int kk = 0; kk < 32; ++kk) {
      float4 a4 = *reinterpret_cast<const float4*>(&Ast[kk][ty * 4]);
      float4 b4 = *reinterpret_cast<const float4*>(&Bst[kk][tx * 4]);
      float a[4] = {a4.x, a4.y, a4.z, a4.w};
      float b[4] = {b4.x, b4.y, b4.z, b4.w};
      #pragma unroll
      for (int i = 0; i < 4; ++i)
        #pragma unroll
        for (int j = 0; j < 4; ++j)
          acc[i][j] += a[i] * b[j];
    }
    __syncthreads();
  }

  #pragma unroll
  for (int i = 0; i < 4; ++i) {
    long long row = m0 + ty * 4 + i;
    float4 o = {acc[i][0], acc[i][1], acc[i][2], acc[i][3]};
    if (BIAS) {
      float4 bb = *reinterpret_cast<const float4*>(&bias[n0 + tx * 4]);
      o.x += bb.x; o.y += bb.y; o.z += bb.z; o.w += bb.w;
    }
    if (RES) {
      float4 rr = *reinterpret_cast<const float4*>(&rp[row * N + n0 + tx * 4]);
      o.x += rr.x; o.y += rr.y; o.z += rr.z; o.w += rr.w;
    }
    if (RELU) {
      o.x = fmaxf(o.x, 0.f); o.y = fmaxf(o.y, 0.f);
      o.z = fmaxf(o.z, 0.f); o.w = fmaxf(o.w, 0.f);
    }
    *reinterpret_cast<float4*>(&C[row * N + n0 + tx * 4]) = o;
  }
}

// ---------------------------------------------------------------------------
// GEMM: C[M,N] = A[M,K] @ Bm[K,N]   (batched, no epilogue) — for w @ vox
// ---------------------------------------------------------------------------
__global__ __launch_bounds__(256)
void gemm_ab(const float* __restrict__ A, const float* __restrict__ Bm,
             float* __restrict__ C, int M, int N, int K,
             long long sA, long long sB, long long sC)
{
  __shared__ float Ast[32][68];
  __shared__ float Bst[32][68];
  const int bz = blockIdx.z;
  A  += (long long)bz * sA;
  Bm += (long long)bz * sB;
  C  += (long long)bz * sC;

  const int m0 = blockIdx.y * 64, n0 = blockIdx.x * 64;
  const int t  = threadIdx.x;
  const int tx = t & 15, ty = t >> 4;
  float acc[4][4] = {};

  for (int k0 = 0; k0 < K; k0 += 32) {
    #pragma unroll
    for (int p = 0; p < 2; ++p) {
      int lin = t + p * 256;
      int row = lin >> 3;          // A: 64 rows x 8 float4
      int c4  = lin & 7;
      float4 a4 = *reinterpret_cast<const float4*>(&A[(long long)(m0 + row) * K + k0 + c4 * 4]);
      Ast[c4 * 4 + 0][row] = a4.x; Ast[c4 * 4 + 1][row] = a4.y;
      Ast[c4 * 4 + 2][row] = a4.z; Ast[c4 * 4 + 3][row] = a4.w;
    }
    #pragma unroll
    for (int p = 0; p < 2; ++p) {
      int lin = t + p * 256;
      int row = lin >> 4;          // B: 32 rows x 16 float4
      int c4  = lin & 15;
      float4 b4 = *reinterpret_cast<const float4*>(&Bm[(long long)(k0 + row) * N + n0 + c4 * 4]);
      *reinterpret_cast<float4*>(&Bst[row][c4 * 4]) = b4;   // row*68 floats -> 16B aligned
    }
    __syncthreads();
    #pragma unroll
    for (int kk = 0; kk < 32; ++kk) {
      float4 a4 = *reinterpret_cast<const float4*>(&Ast[kk][ty * 4]);
      float4 b4 = *reinterpret_cast<const float4*>(&Bst[kk][tx * 4]);
      float a[4] = {a4.x, a4.y, a4.z, a4.w};
      float b[4] = {b4.x, b4.y, b4.z, b4.w};
      #pragma unroll
      for (int i = 0; i < 4; ++i)
        #pragma unroll
        for (int j = 0; j < 4; ++j)
          acc[i][j] += a[i] * b[j];
    }
    __syncthreads();
  }

  #pragma unroll
  for (int i = 0; i < 4; ++i) {
    long long row = m0 + ty * 4 + i;
    float4 o = {acc[i][0], acc[i][1], acc[i][2], acc[i][3]};
    *reinterpret_cast<float4*>(&C[row * N + n0 + tx * 4]) = o;
  }
}

// ---------------------------------------------------------------------------
// MHA over text: one block per (b, q). Computes ctx[b,q,:] and
// out1[b,q,:] = mean over heads of softmax weights.
// ---------------------------------------------------------------------------
__global__ __launch_bounds__(256)
void mha_kernel(const float* __restrict__ q, const float* __restrict__ k,
                const float* __restrict__ v, const int* __restrict__ mask,
                float* __restrict__ ctx, float* __restrict__ out1)
{
  __shared__ float qrow[D];
  __shared__ float sc[LT];
  __shared__ float mw[LT];
  __shared__ float tmp[256];
  const int t  = threadIdx.x;
  const int b  = blockIdx.x / NQ, qi = blockIdx.x % NQ;
  const long long qoff = ((long long)b * NQ + qi) * D;

  *reinterpret_cast<float4*>(&qrow[t * 4]) =
      *reinterpret_cast<const float4*>(&q[qoff + t * 4]);
  mw[t] = 0.f; mw[t + 256] = 0.f;
  __syncthreads();

  for (int h = 0; h < H; ++h) {
    const float* qh = &qrow[h * HD];
    #pragma unroll
    for (int r = 0; r < 2; ++r) {
      int kt = t + r * 256;
      float s;
      if (mask[b * LT + kt]) {
        s = -INFINITY;
      } else {
        const float* kp = &k[((long long)b * LT + kt) * D + h * HD];
        float a = 0.f;
        #pragma unroll
        for (int j = 0; j < 16; ++j) {
          float4 k4 = *reinterpret_cast<const float4*>(&kp[j * 4]);
          float4 q4 = *reinterpret_cast<const float4*>(&qh[j * 4]);
          a += q4.x * k4.x + q4.y * k4.y + q4.z * k4.z + q4.w * k4.w;
        }
        s = a * 0.125f;   // 1/sqrt(64)
      }
      sc[kt] = s;
    }
    __syncthreads();
    // max
    tmp[t] = fmaxf(sc[t], sc[t + 256]);
    __syncthreads();
    for (int off = 128; off > 0; off >>= 1) {
      if (t < off) tmp[t] = fmaxf(tmp[t], tmp[t + off]);
      __syncthreads();
    }
    const float mx = tmp[0];
    __syncthreads();
    // exp + sum
    float e0 = __expf(sc[t] - mx);        // exp(-inf) = 0 handles mask
    float e1 = __expf(sc[t + 256] - mx);
    tmp[t] = e0 + e1;
    __syncthreads();
    for (int off = 128; off > 0; off >>= 1) {
      if (t < off) tmp[t] += tmp[t + off];
      __syncthreads();
    }
    const float inv = 1.f / tmp[0];
    __syncthreads();
    const float w0 = e0 * inv, w1 = e1 * inv;
    sc[t] = w0; sc[t + 256] = w1;
    mw[t] += w0 * (1.f / H); mw[t + 256] += w1 * (1.f / H);
    __syncthreads();
    // ctx_h[d] = sum_k w[k] * v[b,k,h*64+d]; 4 k-chunks of 128 per d
    {
      const int d = t & 63, c = t >> 6;
      const float* vp = &v[((long long)b * LT + c * 128) * D + h * HD + d];
      float a = 0.f;
      for (int kk = 0; kk < 128; ++kk) a += sc[c * 128 + kk] * vp[(long long)kk * D];
      tmp[t] = a;
    }
    __syncthreads();
    if (t < 64) {
      float cv = tmp[t] + tmp[t + 64] + tmp[t + 128] + tmp[t + 192];
      ctx[qoff + h * HD + t] = cv;
    }
    __syncthreads();
  }
  out1[((long long)b * NQ + qi) * LT + t]       = mw[t];
  out1[((long long)b * NQ + qi) * LT + t + 256] = mw[t + 256];
}

// ---------------------------------------------------------------------------
// LayerNorm over rows of D=1024; y = ((x-m)*rsqrt(v+eps)*g + b) * scale
// ---------------------------------------------------------------------------
__global__ __launch_bounds__(256)
void ln_kernel(const float* __restrict__ x, const float* __restrict__ g,
               const float* __restrict__ bia, float* __restrict__ y, float scale)
{
  __shared__ float tmp[256];
  const int t = threadIdx.x;
  const long long off = (long long)blockIdx.x * D;
  float4 x4 = *reinterpret_cast<const float4*>(&x[off + t * 4]);
  tmp[t] = x4.x + x4.y + x4.z + x4.w;
  __syncthreads();
  for (int o = 128; o > 0; o >>= 1) { if (t < o) tmp[t] += tmp[t + o]; __syncthreads(); }
  const float mean = tmp[0] * (1.f / D);
  __syncthreads();
  float d0 = x4.x - mean, d1 = x4.y - mean, d2 = x4.z - mean, d3 = x4.w - mean;
  tmp[t] = d0 * d0 + d1 * d1 + d2 * d2 + d3 * d3;
  __syncthreads();
  for (int o = 128; o > 0; o >>= 1) { if (t < o) tmp[t] += tmp[t + o]; __syncthreads(); }
  const float rs = rsqrtf(tmp[0] * (1.f / D) + 1e-5f);
  float4 g4 = *reinterpret_cast<const float4*>(&g[t * 4]);
  float4 b4 = *reinterpret_cast<const float4*>(&bia[t * 4]);
  float4 o4;
  o4.x = (d0 * rs * g4.x + b4.x) * scale;
  o4.y = (d1 * rs * g4.y + b4.y) * scale;
  o4.z = (d2 * rs * g4.z + b4.z) * scale;
  o4.w = (d3 * rs * g4.w + b4.w) * scale;
  *reinterpret_cast<float4*>(&y[off + t * 4]) = o4;
}

// ---------------------------------------------------------------------------
// Masked softmax over rows of NV=4096, in place (on out2).
// ---------------------------------------------------------------------------
__global__ __launch_bounds__(256)
void vox_softmax(float* __restrict__ s, const int* __restrict__ mask)
{
  __shared__ float tmp[256];
  const int t = threadIdx.x;
  const int row = blockIdx.x, b = row / NQ;
  float* sr = s + (long long)row * NV;
  const int* mr = mask + b * NV;
  float vals[16];
  float lm = -INFINITY;
  #pragma unroll
  for (int j = 0; j < 16; ++j) {
    int n = t + j * 256;
    float x = sr[n];
    if (mr[n]) x = -INFINITY;
    vals[j] = x;
    lm = fmaxf(lm, x);
  }
  tmp[t] = lm;
  __syncthreads();
  for (int o = 128; o > 0; o >>= 1) { if (t < o) tmp[t] = fmaxf(tmp[t], tmp[t + o]); __syncthreads(); }
  const float mx = tmp[0];
  __syncthreads();
  float ls = 0.f;
  #pragma unroll
  for (int j = 0; j < 16; ++j) { vals[j] = __expf(vals[j] - mx); ls += vals[j]; }
  tmp[t] = ls;
  __syncthreads();
  for (int o = 128; o > 0; o >>= 1) { if (t < o) tmp[t] += tmp[t + o]; __syncthreads(); }
  const float inv = 1.f / tmp[0];
  #pragma unroll
  for (int j = 0; j < 16; ++j) sr[t + j * 256] = vals[j] * inv;
}

// ---------------------------------------------------------------------------
extern "C" void kernel_launch(void* const* d_in, const int* in_sizes, int n_in,
                              void* d_out, int out_size, void* d_ws, size_t ws_size,
                              hipStream_t stream)
{
  const float* tgt   = (const float*)d_in[0];
  const float* mtxt  = (const float*)d_in[1];
  const float* vox   = (const float*)d_in[2];
  const float* qpos  = (const float*)d_in[3];
  const int*   mtx_m = (const int*)d_in[4];
  const int*   vox_m = (const int*)d_in[5];
  const float* Wq = (const float*)d_in[6];  const float* bq = (const float*)d_in[7];
  const float* Wk = (const float*)d_in[8];  const float* bk = (const float*)d_in[9];
  const float* Wv = (const float*)d_in[10]; const float* bv = (const float*)d_in[11];
  const float* Wo = (const float*)d_in[12]; const float* bo = (const float*)d_in[13];
  const float* W1 = (const float*)d_in[14]; const float* b1 = (const float*)d_in[15];
  const float* W2 = (const float*)d_in[16]; const float* b2 = (const float*)d_in[17];
  const float* ln1g = (const float*)d_in[18]; const float* ln1b = (const float*)d_in[19];
  const float* ln2g = (const float*)d_in[20]; const float* ln2b = (const float*)d_in[21];

  float* out  = (float*)d_out;
  float* out0 = out;                               // attn_output  [B,NQ,D]
  float* out1 = out0 + (long long)B * NQ * D;      // txt_cross    [B,NQ,LT]
  float* out2 = out1 + (long long)B * NQ * LT;     // attn_weights [B,NQ,NV]

  // workspace (floats): q | k | v | ctx | x1pre | x1   (67 MB total)
  float* ws   = (float*)d_ws;
  float* q    = ws;                      // 2,097,152   (reused later as x2s)
  float* k    = q   + (long long)B*NQ*D; // 4,194,304   (reused later as ff1)
  float* v    = k   + (long long)B*LT*D; // 4,194,304   (reused later as x2pre)
  float* ctx  = v   + (long long)B*LT*D; // 2,097,152
  float* x1p  = ctx + (long long)B*NQ*D; // 2,097,152
  float* x1   = x1p + (long long)B*NQ*D; // 2,097,152
  float* ff1  = k;
  float* x2p  = v;
  float* x2s  = q;

  const dim3 blk(256);

  // 1) q = (tgt + query_pos) @ Wq^T + bq
  gemm_abt<true, true, false, false><<<dim3(D/64, (B*NQ)/64, 1), blk, 0, stream>>>(
      tgt, qpos, Wq, bq, nullptr, q, B*NQ, D, D, 0, 0, 0);
  // 2) k = memory_txt @ Wk^T + bk
  gemm_abt<false, true, false, false><<<dim3(D/64, (B*LT)/64, 1), blk, 0, stream>>>(
      mtxt, nullptr, Wk, bk, nullptr, k, B*LT, D, FTXT, 0, 0, 0);
  // 3) v = memory_txt @ Wv^T + bv
  gemm_abt<false, true, false, false><<<dim3(D/64, (B*LT)/64, 1), blk, 0, stream>>>(
      mtxt, nullptr, Wv, bv, nullptr, v, B*LT, D, FTXT, 0, 0, 0);
  // 4) MHA -> ctx, out1
  mha_kernel<<<dim3(B*NQ), blk, 0, stream>>>(q, k, v, mtx_m, ctx, out1);
  // 5) x1pre = tgt + ctx @ Wo^T + bo
  gemm_abt<false, true, false, true><<<dim3(D/64, (B*NQ)/64, 1), blk, 0, stream>>>(
      ctx, nullptr, Wo, bo, tgt, x1p, B*NQ, D, D, 0, 0, 0);
  // 6) x1 = LN1(x1pre)
  ln_kernel<<<dim3(B*NQ), blk, 0, stream>>>(x1p, ln1g, ln1b, x1, 1.0f);
  // 7) ff1 = relu(x1 @ W1^T + b1)
  gemm_abt<false, true, true, false><<<dim3(DFF/64, (B*NQ)/64, 1), blk, 0, stream>>>(
      x1, nullptr, W1, b1, nullptr, ff1, B*NQ, DFF, D, 0, 0, 0);
  // 8) x2pre = x1 + ff1 @ W2^T + b2
  gemm_abt<false, true, false, true><<<dim3(D/64, (B*NQ)/64, 1), blk, 0, stream>>>(
      ff1, nullptr, W2, b2, x1, x2p, B*NQ, D, DFF, 0, 0, 0);
  // 9) x2s = LN2(x2pre) / sqrt(D)
  ln_kernel<<<dim3(B*NQ), blk, 0, stream>>>(x2p, ln2g, ln2b, x2s, 0.03125f);
  // 10) out2 = x2s @ vox^T  (batched, raw scores)
  gemm_abt<false, false, false, false><<<dim3(NV/64, NQ/64, B), blk, 0, stream>>>(
      x2s, nullptr, vox, nullptr, nullptr, out2,
      NQ, NV, D, (long long)NQ*D, (long long)NV*D, (long long)NQ*NV);
  // 11) masked softmax rows of out2 (in place)
  vox_softmax<<<dim3(B*NQ), blk, 0, stream>>>(out2, vox_m);
  // 12) out0 = out2 @ vox  (batched)
  gemm_ab<<<dim3(D/64, NQ/64, B), blk, 0, stream>>>(
      out2, vox, out0, NQ, D, NV,
      (long long)NQ*NV, (long long)NV*D, (long long)NQ*D);
}

// Round 2
// 783.209 us; speedup vs baseline: 3.1107x; 3.1107x over previous
//
#include <hip/hip_runtime.h>
#include <math.h>

typedef unsigned short u16;
typedef unsigned int u32;
typedef __bf16 bf16x8 __attribute__((ext_vector_type(8)));
typedef float f32x4 __attribute__((ext_vector_type(4)));
typedef u16 u16x4 __attribute__((ext_vector_type(4)));

constexpr int B = 8, NQ = 256, LT = 512, NV = 4096;
constexpr int D = 1024, H = 16, DFF = 2048, FTXT = 4096, HD = 64;

__device__ __forceinline__ u16 f2b(float f) {
  u32 u = __builtin_bit_cast(u32, f);
  return (u16)((u + 0x7fffu + ((u >> 16) & 1u)) >> 16);   // RNE
}
__device__ __forceinline__ float b2f(u16 b) {
  u32 u = ((u32)b) << 16;
  return __builtin_bit_cast(float, u);
}
__device__ __forceinline__ void gload16(const void* g, void* l) {
  __builtin_amdgcn_global_load_lds(
      (const __attribute__((address_space(1))) u32*)g,
      (__attribute__((address_space(3))) u32*)l, 16, 0, 0);
}

// ---------------------------------------------------------------------------
// bf16 MFMA GEMM (m97 structure): C[M,N] = alpha * A[M,K] @ Bw[N,K]^T (+bias)
// (+res f32) (relu?), writes f32 C and/or bf16 Cb. 256 thr = 4 waves (WM x WN),
// BK=32, LDS linear [BM][32] + [BN][32] bf16, staged via global_load_lds x16B.
// Batched: bz decomposed as (bz/nbz2, bz%nbz2) with two strides per tensor.
// ---------------------------------------------------------------------------
constexpr int E_BIAS = 1, E_RES = 2, E_RELU = 4, E_WF32 = 8, E_WB16 = 16;

template<int BM, int BN, int WM, int WN, int EPI>
__global__ __launch_bounds__(256)
void gemm_bf16(const u16* __restrict__ A, const u16* __restrict__ Bw,
               const float* __restrict__ bias, const float* __restrict__ res,
               float* __restrict__ C, u16* __restrict__ Cb,
               int K, int lda, int ldb, int ldc, int nbz2,
               long long sA1, long long sA2, long long sB1, long long sB2,
               long long sC1, long long sC2, float alpha)
{
  constexpr int SM = BM / WM, SN = BN / WN;
  constexpr int FM = SM / 16, FN = SN / 16;
  constexpr int PA = BM / 64, PB = BN / 64;
  __shared__ __align__(16) u16 As[BM * 32];
  __shared__ __align__(16) u16 Bs[BN * 32];

  const int t = threadIdx.x;
  const int w = t >> 6, l = t & 63;
  const int wr = w / WN, wc = w % WN;
  const int bz = blockIdx.z;
  const int m0 = blockIdx.y * BM, n0 = blockIdx.x * BN;
  const long long offA = (long long)(bz / nbz2) * sA1 + (long long)(bz % nbz2) * sA2;
  const long long offB = (long long)(bz / nbz2) * sB1 + (long long)(bz % nbz2) * sB2;
  const long long offC = (long long)(bz / nbz2) * sC1 + (long long)(bz % nbz2) * sC2;
  const u16* Ab = A + offA;
  const u16* Bb = Bw + offB;

  const int srow = t >> 2;          // 0..63 staging row within 64-row group
  const int sk   = (t & 3) * 8;     // staging k-element offset (8 bf16 = 16B)

  f32x4 acc[FM][FN] = {};

  for (int k0 = 0; k0 < K; k0 += 32) {
    #pragma unroll
    for (int p = 0; p < PA; ++p)
      gload16(&Ab[(long long)(m0 + p * 64 + srow) * lda + k0 + sk],
              &As[p * 2048 + w * 512]);
    #pragma unroll
    for (int p = 0; p < PB; ++p)
      gload16(&Bb[(long long)(n0 + p * 64 + srow) * ldb + k0 + sk],
              &Bs[p * 2048 + w * 512]);
    __syncthreads();

    bf16x8 af[FM], bfr[FN];
    #pragma unroll
    for (int i = 0; i < FM; ++i)
      af[i] = *reinterpret_cast<const bf16x8*>(
          &As[(wr * SM + i * 16 + (l & 15)) * 32 + (l >> 4) * 8]);
    #pragma unroll
    for (int j = 0; j < FN; ++j)
      bfr[j] = *reinterpret_cast<const bf16x8*>(
          &Bs[(wc * SN + j * 16 + (l & 15)) * 32 + (l >> 4) * 8]);
    #pragma unroll
    for (int i = 0; i < FM; ++i)
      #pragma unroll
      for (int j = 0; j < FN; ++j)
        acc[i][j] = __builtin_amdgcn_mfma_f32_16x16x32_bf16(af[i], bfr[j], acc[i][j], 0, 0, 0);
    __syncthreads();
  }

  const int c_l = l & 15, r_l4 = (l >> 4) * 4;
  #pragma unroll
  for (int i = 0; i < FM; ++i) {
    #pragma unroll
    for (int r = 0; r < 4; ++r) {
      const long long row = m0 + wr * SM + i * 16 + r_l4 + r;
      #pragma unroll
      for (int j = 0; j < FN; ++j) {
        const int col = n0 + wc * SN + j * 16 + c_l;
        float v = acc[i][j][r] * alpha;
        if (EPI & E_BIAS) v += bias[col];
        if (EPI & E_RES)  v += res[row * (long long)ldc + col];
        if (EPI & E_RELU) v = fmaxf(v, 0.f);
        const long long co = offC + row * (long long)ldc + col;
        if (EPI & E_WF32) C[co] = v;
        if (EPI & E_WB16) Cb[co] = f2b(v);
      }
    }
  }
}

// ---------------------------------------------------------------------------
// f32 -> bf16 conversion (4 elems/thread); n % 1024 == 0
// ---------------------------------------------------------------------------
__global__ __launch_bounds__(256)
void cvt_bf16(const float* __restrict__ in, u16* __restrict__ out)
{
  const long long i = ((long long)blockIdx.x * 256 + threadIdx.x) * 4;
  float4 x = *reinterpret_cast<const float4*>(&in[i]);
  u16x4 o = {f2b(x.x), f2b(x.y), f2b(x.z), f2b(x.w)};
  *reinterpret_cast<u16x4*>(&out[i]) = o;
}

__global__ __launch_bounds__(256)
void cvt_add_bf16(const float* __restrict__ a, const float* __restrict__ b,
                  u16* __restrict__ out)
{
  const long long i = ((long long)blockIdx.x * 256 + threadIdx.x) * 4;
  float4 x = *reinterpret_cast<const float4*>(&a[i]);
  float4 y = *reinterpret_cast<const float4*>(&b[i]);
  u16x4 o = {f2b(x.x + y.x), f2b(x.y + y.y), f2b(x.z + y.z), f2b(x.w + y.w)};
  *reinterpret_cast<u16x4*>(&out[i]) = o;
}

// ---------------------------------------------------------------------------
// Transpose f32 [nb][R][C] -> bf16 [nb][C][R]
// ---------------------------------------------------------------------------
__global__ __launch_bounds__(256)
void transpose_cvt(const float* __restrict__ in, u16* __restrict__ out, int R, int C)
{
  __shared__ float tile[32][33];
  const int b = blockIdx.z;
  const int r0 = blockIdx.y * 32, c0 = blockIdx.x * 32;
  const int tx = threadIdx.x & 31, ty = threadIdx.x >> 5;
  const float* ib = in + (long long)b * R * C;
  u16* ob = out + (long long)b * R * C;
  #pragma unroll
  for (int p = 0; p < 4; ++p) {
    int r = ty + p * 8;
    tile[r][tx] = ib[(long long)(r0 + r) * C + c0 + tx];
  }
  __syncthreads();
  #pragma unroll
  for (int p = 0; p < 4; ++p) {
    int c = ty + p * 8;
    ob[(long long)(c0 + c) * R + r0 + tx] = f2b(tile[tx][c]);
  }
}

// Transpose u16 [nb][R][C] -> u16 [nb][C][R]
__global__ __launch_bounds__(256)
void transpose_u16(const u16* __restrict__ in, u16* __restrict__ out, int R, int C)
{
  __shared__ u16 tile[32][34];
  const int b = blockIdx.z;
  const int r0 = blockIdx.y * 32, c0 = blockIdx.x * 32;
  const int tx = threadIdx.x & 31, ty = threadIdx.x >> 5;
  const u16* ib = in + (long long)b * R * C;
  u16* ob = out + (long long)b * R * C;
  #pragma unroll
  for (int p = 0; p < 4; ++p) {
    int r = ty + p * 8;
    tile[r][tx] = ib[(long long)(r0 + r) * C + c0 + tx];
  }
  __syncthreads();
  #pragma unroll
  for (int p = 0; p < 4; ++p) {
    int c = ty + p * 8;
    ob[(long long)(c0 + c) * R + r0 + tx] = tile[tx][c];
  }
}

// ---------------------------------------------------------------------------
// Masked softmax over rows of LT=512 (txt): scores f32 -> w bf16
// row index = b*H*NQ + h*NQ + q;  mask[b][l]
// ---------------------------------------------------------------------------
__global__ __launch_bounds__(256)
void txt_softmax(const float* __restrict__ sc, const int* __restrict__ mask,
                 u16* __restrict__ wout)
{
  __shared__ float tmp[256];
  const int t = threadIdx.x;
  const int row = blockIdx.x;
  const int b = row >> 12;                      // H*NQ = 4096
  const float* sr = sc + (long long)row * LT;
  u16* wr = wout + (long long)row * LT;
  const int* mr = mask + b * LT;
  float x0 = mr[t]       ? -INFINITY : sr[t];
  float x1 = mr[t + 256] ? -INFINITY : sr[t + 256];
  tmp[t] = fmaxf(x0, x1);
  __syncthreads();
  for (int o = 128; o > 0; o >>= 1) { if (t < o) tmp[t] = fmaxf(tmp[t], tmp[t + o]); __syncthreads(); }
  const float mx = tmp[0];
  __syncthreads();
  float e0 = __expf(x0 - mx), e1 = __expf(x1 - mx);
  tmp[t] = e0 + e1;
  __syncthreads();
  for (int o = 128; o > 0; o >>= 1) { if (t < o) tmp[t] += tmp[t + o]; __syncthreads(); }
  const float inv = 1.f / tmp[0];
  wr[t]       = f2b(e0 * inv);
  wr[t + 256] = f2b(e1 * inv);
}

// out1[b,q,l] = mean over h of w_bf[b,h,q,l]
__global__ __launch_bounds__(256)
void head_mean(const u16* __restrict__ w, float* __restrict__ out1)
{
  const long long idx = (long long)blockIdx.x * 256 + threadIdx.x;  // B*NQ*LT
  const int b = (int)(idx >> 17);               // NQ*LT = 131072
  const long long ql = idx & 131071;
  const u16* p = w + ((long long)b * H) * 131072 + ql;
  float s = 0.f;
  #pragma unroll
  for (int h = 0; h < H; ++h) s += b2f(p[(long long)h * 131072]);
  out1[idx] = s * (1.f / H);
}

// ---------------------------------------------------------------------------
// LayerNorm over D=1024; writes f32 y (if non-null) and bf16 yb (if non-null),
// both scaled by `scale` after affine.
// ---------------------------------------------------------------------------
__global__ __launch_bounds__(256)
void ln_kernel(const float* __restrict__ x, const float* __restrict__ g,
               const float* __restrict__ bia, float* __restrict__ y,
               u16* __restrict__ yb, float scale)
{
  __shared__ float tmp[256];
  const int t = threadIdx.x;
  const long long off = (long long)blockIdx.x * D;
  float4 x4 = *reinterpret_cast<const float4*>(&x[off + t * 4]);
  tmp[t] = x4.x + x4.y + x4.z + x4.w;
  __syncthreads();
  for (int o = 128; o > 0; o >>= 1) { if (t < o) tmp[t] += tmp[t + o]; __syncthreads(); }
  const float mean = tmp[0] * (1.f / D);
  __syncthreads();
  float d0 = x4.x - mean, d1 = x4.y - mean, d2 = x4.z - mean, d3 = x4.w - mean;
  tmp[t] = d0 * d0 + d1 * d1 + d2 * d2 + d3 * d3;
  __syncthreads();
  for (int o = 128; o > 0; o >>= 1) { if (t < o) tmp[t] += tmp[t + o]; __syncthreads(); }
  const float rs = rsqrtf(tmp[0] * (1.f / D) + 1e-5f);
  float4 g4 = *reinterpret_cast<const float4*>(&g[t * 4]);
  float4 b4 = *reinterpret_cast<const float4*>(&bia[t * 4]);
  float o0 = (d0 * rs * g4.x + b4.x) * scale;
  float o1 = (d1 * rs * g4.y + b4.y) * scale;
  float o2 = (d2 * rs * g4.z + b4.z) * scale;
  float o3 = (d3 * rs * g4.w + b4.w) * scale;
  if (y) {
    float4 o4 = {o0, o1, o2, o3};
    *reinterpret_cast<float4*>(&y[off + t * 4]) = o4;
  }
  if (yb) {
    u16x4 ob = {f2b(o0), f2b(o1), f2b(o2), f2b(o3)};
    *reinterpret_cast<u16x4*>(&yb[off + t * 4]) = ob;
  }
}

// ---------------------------------------------------------------------------
// Masked softmax over rows of NV=4096, in place on f32 s; also writes bf16 wb.
// ---------------------------------------------------------------------------
__global__ __launch_bounds__(256)
void vox_softmax(float* __restrict__ s, const int* __restrict__ mask,
                 u16* __restrict__ wb)
{
  __shared__ float tmp[256];
  const int t = threadIdx.x;
  const int row = blockIdx.x, b = row / NQ;
  float* sr = s + (long long)row * NV;
  u16* wr = wb + (long long)row * NV;
  const int* mr = mask + b * NV;
  float vals[16];
  float lm = -INFINITY;
  #pragma unroll
  for (int j = 0; j < 16; ++j) {
    int n = t + j * 256;
    float x = mr[n] ? -INFINITY : sr[n];
    vals[j] = x;
    lm = fmaxf(lm, x);
  }
  tmp[t] = lm;
  __syncthreads();
  for (int o = 128; o > 0; o >>= 1) { if (t < o) tmp[t] = fmaxf(tmp[t], tmp[t + o]); __syncthreads(); }
  const float mx = tmp[0];
  __syncthreads();
  float ls = 0.f;
  #pragma unroll
  for (int j = 0; j < 16; ++j) { vals[j] = __expf(vals[j] - mx); ls += vals[j]; }
  tmp[t] = ls;
  __syncthreads();
  for (int o = 128; o > 0; o >>= 1) { if (t < o) tmp[t] += tmp[t + o]; __syncthreads(); }
  const float inv = 1.f / tmp[0];
  #pragma unroll
  for (int j = 0; j < 16; ++j) {
    float v = vals[j] * inv;
    sr[t + j * 256] = v;
    wr[t + j * 256] = f2b(v);
  }
}

// ---------------------------------------------------------------------------
extern "C" void kernel_launch(void* const* d_in, const int* in_sizes, int n_in,
                              void* d_out, int out_size, void* d_ws, size_t ws_size,
                              hipStream_t stream)
{
  const float* tgt   = (const float*)d_in[0];
  const float* mtxt  = (const float*)d_in[1];
  const float* vox   = (const float*)d_in[2];
  const float* qpos  = (const float*)d_in[3];
  const int*   mtx_m = (const int*)d_in[4];
  const int*   vox_m = (const int*)d_in[5];
  const float* Wq = (const float*)d_in[6];  const float* bq = (const float*)d_in[7];
  const float* Wk = (const float*)d_in[8];  const float* bk = (const float*)d_in[9];
  const float* Wv = (const float*)d_in[10]; const float* bv = (const float*)d_in[11];
  const float* Wo = (const float*)d_in[12]; const float* bo = (const float*)d_in[13];
  const float* W1 = (const float*)d_in[14]; const float* b1 = (const float*)d_in[15];
  const float* W2 = (const float*)d_in[16]; const float* b2 = (const float*)d_in[17];
  const float* ln1g = (const float*)d_in[18]; const float* ln1b = (const float*)d_in[19];
  const float* ln2g = (const float*)d_in[20]; const float* ln2b = (const float*)d_in[21];

  float* out0 = (float*)d_out;                       // attn_output  [B,NQ,D]
  float* out1 = out0 + (long long)B * NQ * D;        // txt_cross    [B,NQ,LT]
  float* out2 = out1 + (long long)B * NQ * LT;       // attn_weights [B,NQ,NV]

  // --- workspace layout (byte offsets, MiB units). Peak = 232 MiB. ---
  char* base = (char*)d_ws;
  constexpr size_t MB = 1ull << 20;
  u16*   Wq_b  = (u16*)(base + 0 * MB);     // 2
  u16*   Wk_b  = (u16*)(base + 2 * MB);     // 8
  u16*   Wv_b  = (u16*)(base + 10 * MB);    // 8
  u16*   Wo_b  = (u16*)(base + 18 * MB);    // 2
  u16*   W1_b  = (u16*)(base + 20 * MB);    // 4
  u16*   W2_b  = (u16*)(base + 24 * MB);    // 4
  u16*   tq_b  = (u16*)(base + 28 * MB);    // 4
  u16*   q_b   = (u16*)(base + 32 * MB);    // 4
  u16*   k_b   = (u16*)(base + 36 * MB);    // 8
  u16*   v_b   = (u16*)(base + 44 * MB);    // 8
  u16*   vT_b  = (u16*)(base + 52 * MB);    // 8
  u16*   ctx_b = (u16*)(base + 60 * MB);    // 4
  float* x1p   = (float*)(base + 64 * MB);  // 8
  float* x1f   = (float*)(base + 72 * MB);  // 8
  u16*   x1_b  = (u16*)(base + 80 * MB);    // 4
  u16*   ff1_b = (u16*)(base + 84 * MB);    // 8
  float* x2p   = (float*)(base + 92 * MB);  // 8
  u16*   x2s_b = (u16*)(base + 100 * MB);   // 4
  u16*   mtxt_b = (u16*)(base + 104 * MB);  // 32  (dead after v-proj)
  float* scores = (float*)(base + 136 * MB);// 64  (dead after txt_softmax)
  u16*   w_b    = (u16*)(base + 200 * MB);  // 32  (dead after ctx gemm)
  u16*   vox_b  = (u16*)(base + 104 * MB);  // 64  overlays mtxt+scores (both dead)
  u16*   voxT_b = (u16*)(base + 168 * MB);  // 64  overlays scores tail + w_b (dead)
  u16*   wvox_b = (u16*)(base + 104 * MB);  // 16  overlays vox_b (dead after vox-score gemm)

  const dim3 blk(256);
  // strides (elements)
  const long long sQ = (long long)NQ * D;      // 262144
  const long long sKV = (long long)LT * D;     // 524288
  const long long sSC = (long long)NQ * LT;    // 131072

  // 1) convert weights + fused (tgt+qpos) + memory_txt to bf16
  cvt_bf16<<<dim3((D * D) / 1024), blk, 0, stream>>>(Wq, Wq_b);
  cvt_bf16<<<dim3((D * FTXT) / 1024), blk, 0, stream>>>(Wk, Wk_b);
  cvt_bf16<<<dim3((D * FTXT) / 1024), blk, 0, stream>>>(Wv, Wv_b);
  cvt_bf16<<<dim3((D * D) / 1024), blk, 0, stream>>>(Wo, Wo_b);
  cvt_bf16<<<dim3((DFF * D) / 1024), blk, 0, stream>>>(W1, W1_b);
  cvt_bf16<<<dim3((D * DFF) / 1024), blk, 0, stream>>>(W2, W2_b);
  cvt_add_bf16<<<dim3((B * NQ * D) / 1024), blk, 0, stream>>>(tgt, qpos, tq_b);
  cvt_bf16<<<dim3((B * LT * FTXT) / 1024), blk, 0, stream>>>(mtxt, mtxt_b);

  // 2) projections: q = tq @ Wq^T + bq ; k,v = mtxt @ W^T + b  (bf16 out)
  gemm_bf16<128,128,2,2, E_BIAS|E_WB16><<<dim3(D/128, (B*NQ)/128, 1), blk, 0, stream>>>(
      tq_b, Wq_b, bq, nullptr, nullptr, q_b, D, D, D, D, 1, 0,0,0,0,0,0, 1.f);
  gemm_bf16<128,128,2,2, E_BIAS|E_WB16><<<dim3(D/128, (B*LT)/128, 1), blk, 0, stream>>>(
      mtxt_b, Wk_b, bk, nullptr, nullptr, k_b, FTXT, FTXT, FTXT, D, 1, 0,0,0,0,0,0, 1.f);
  gemm_bf16<128,128,2,2, E_BIAS|E_WB16><<<dim3(D/128, (B*LT)/128, 1), blk, 0, stream>>>(
      mtxt_b, Wv_b, bv, nullptr, nullptr, v_b, FTXT, FTXT, FTXT, D, 1, 0,0,0,0,0,0, 1.f);

  // 3) vT[b][d][l] = v[b][l][d]
  transpose_u16<<<dim3(D/32, LT/32, B), blk, 0, stream>>>(v_b, vT_b, LT, D);

  // 4) scores[b,h,q,l] = (q_h . k_h) / 8   (batched over B*H)
  gemm_bf16<128,128,2,2, E_WF32><<<dim3(LT/128, NQ/128, B*H), blk, 0, stream>>>(
      q_b, k_b, nullptr, nullptr, scores, nullptr, HD, D, D, LT, H,
      sQ, HD, sKV, HD, (long long)H*sSC, sSC, 0.125f);

  // 5) softmax rows -> w bf16 ; out1 = head mean
  txt_softmax<<<dim3(B*H*NQ), blk, 0, stream>>>(scores, mtx_m, w_b);
  cvt_bf16<<<dim3((B * NV * D) / 1024), blk, 0, stream>>>(vox, vox_b);  // scores region free soon; vox_b overlays mtxt+scores[0:32]
  head_mean<<<dim3((B*NQ*LT)/256), blk, 0, stream>>>(w_b, out1);

  // 6) ctx[b,q,(h,d)] = w_h @ v_h   (batched over B*H; N=HD=64)
  gemm_bf16<128,64,4,1, E_WB16><<<dim3(HD/64, NQ/128, B*H), blk, 0, stream>>>(
      w_b, vT_b, nullptr, nullptr, nullptr, ctx_b, LT, LT, LT, D, H,
      (long long)H*sSC, sSC, sKV, (long long)HD*LT, sQ, HD, 1.f);

  // 7) x1p = tgt + ctx @ Wo^T + bo
  gemm_bf16<128,128,2,2, E_BIAS|E_RES|E_WF32><<<dim3(D/128, (B*NQ)/128, 1), blk, 0, stream>>>(
      ctx_b, Wo_b, bo, tgt, x1p, nullptr, D, D, D, D, 1, 0,0,0,0,0,0, 1.f);

  // 8) voxT[b][d][n] = vox[b][n][d]  (f32 -> bf16; scores & w_b now dead)
  transpose_cvt<<<dim3(D/32, NV/32, B), blk, 0, stream>>>(vox, voxT_b, NV, D);

  // 9) LN1 -> x1 (f32 + bf16)
  ln_kernel<<<dim3(B*NQ), blk, 0, stream>>>(x1p, ln1g, ln1b, x1f, x1_b, 1.f);

  // 10) ff1 = relu(x1 @ W1^T + b1)  (bf16)
  gemm_bf16<128,128,2,2, E_BIAS|E_RELU|E_WB16><<<dim3(DFF/128, (B*NQ)/128, 1), blk, 0, stream>>>(
      x1_b, W1_b, b1, nullptr, nullptr, ff1_b, D, D, D, DFF, 1, 0,0,0,0,0,0, 1.f);

  // 11) x2p = x1 + ff1 @ W2^T + b2
  gemm_bf16<128,128,2,2, E_BIAS|E_RES|E_WF32><<<dim3(D/128, (B*NQ)/128, 1), blk, 0, stream>>>(
      ff1_b, W2_b, b2, x1f, x2p, nullptr, DFF, DFF, DFF, D, 1, 0,0,0,0,0,0, 1.f);

  // 12) LN2 -> x2s (bf16, scaled by 1/sqrt(D))
  ln_kernel<<<dim3(B*NQ), blk, 0, stream>>>(x2p, ln2g, ln2b, nullptr, x2s_b, 0.03125f);

  // 13) out2 = x2s @ vox^T  (f32 scores, batched over B)
  gemm_bf16<128,128,2,2, E_WF32><<<dim3(NV/128, NQ/128, B), blk, 0, stream>>>(
      x2s_b, vox_b, nullptr, nullptr, out2, nullptr, D, D, D, NV, 1,
      sQ, 0, (long long)NV*D, 0, (long long)NQ*NV, 0, 1.f);

  // 14) masked softmax in place on out2; also write bf16 weights
  vox_softmax<<<dim3(B*NQ), blk, 0, stream>>>(out2, vox_m, wvox_b);

  // 15) out0 = w_vox @ vox  (via voxT as B^T operand; batched over B)
  gemm_bf16<128,128,2,2, E_WF32><<<dim3(D/128, NQ/128, B), blk, 0, stream>>>(
      wvox_b, voxT_b, nullptr, nullptr, out0, nullptr, NV, NV, NV, D, 1,
      (long long)NQ*NV, 0, (long long)D*NV, 0, sQ, 0, 1.f);
}

// Round 3
// 486.043 us; speedup vs baseline: 5.0125x; 1.6114x over previous
//
#include <hip/hip_runtime.h>
#include <math.h>

typedef unsigned short u16;
typedef unsigned int u32;
typedef __bf16 bf16x8 __attribute__((ext_vector_type(8)));
typedef float f32x4 __attribute__((ext_vector_type(4)));
typedef u16 u16x4 __attribute__((ext_vector_type(4)));

constexpr int B = 8, NQ = 256, LT = 512, NV = 4096;
constexpr int D = 1024, H = 16, DFF = 2048, FTXT = 4096, HD = 64;

__device__ __forceinline__ u16 f2b(float f) {
  u32 u = __builtin_bit_cast(u32, f);
  return (u16)((u + 0x7fffu + ((u >> 16) & 1u)) >> 16);   // RNE
}
__device__ __forceinline__ float b2f(u16 b) {
  u32 u = ((u32)b) << 16;
  return __builtin_bit_cast(float, u);
}
__device__ __forceinline__ void gload16(const void* g, void* l) {
  __builtin_amdgcn_global_load_lds(
      (const __attribute__((address_space(1))) u32*)g,
      (__attribute__((address_space(3))) u32*)l, 16, 0, 0);
}

// ---------------------------------------------------------------------------
// bf16 MFMA GEMM: C[M,N] = alpha * A[M,K] @ Bw[N,K]^T (+bias)(+res)(relu?)
// 2-phase double-buffered LDS staging (stage t+1 before compute t, one
// barrier/K-step) + XCD-bijective block swizzle (m204).
// Batched: bz = (bz/nbz2, bz%nbz2) with two strides per tensor.
// ---------------------------------------------------------------------------
constexpr int E_BIAS = 1, E_RES = 2, E_RELU = 4, E_WF32 = 8, E_WB16 = 16;

template<int BM, int BN, int WM, int WN, int EPI>
__global__ __launch_bounds__(256)
void gemm_bf16(const u16* __restrict__ A, const u16* __restrict__ Bw,
               const float* __restrict__ bias, const float* __restrict__ res,
               float* __restrict__ C, u16* __restrict__ Cb,
               int K, int lda, int ldb, int ldc, int nbz2,
               long long sA1, long long sA2, long long sB1, long long sB2,
               long long sC1, long long sC2, float alpha)
{
  constexpr int SM = BM / WM, SN = BN / WN;
  constexpr int FM = SM / 16, FN = SN / 16;
  constexpr int PA = BM / 64, PB = BN / 64;
  __shared__ __align__(16) u16 As[2][BM * 32];
  __shared__ __align__(16) u16 Bs[2][BN * 32];

  // --- XCD-aware bijective swizzle (m204) over the flattened grid ---
  const int gx = gridDim.x, gy = gridDim.y;
  const int nwg = gx * gy * gridDim.z;
  const int flat = (blockIdx.z * gy + blockIdx.y) * gx + blockIdx.x;
  const int qq = nwg >> 3, rr = nwg & 7;
  const int xcd = flat & 7, lid = flat >> 3;
  const int wg = (xcd < rr ? xcd * (qq + 1) : rr * (qq + 1) + (xcd - rr) * qq) + lid;
  const int bx = wg % gx;
  const int tmp1 = wg / gx;
  const int by = tmp1 % gy, bz = tmp1 / gy;

  const int t = threadIdx.x;
  const int w = t >> 6, l = t & 63;
  const int wr = w / WN, wc = w % WN;
  const int m0 = by * BM, n0 = bx * BN;
  const long long offA = (long long)(bz / nbz2) * sA1 + (long long)(bz % nbz2) * sA2;
  const long long offB = (long long)(bz / nbz2) * sB1 + (long long)(bz % nbz2) * sB2;
  const long long offC = (long long)(bz / nbz2) * sC1 + (long long)(bz % nbz2) * sC2;
  const u16* Ab = A + offA;
  const u16* Bb = Bw + offB;

  const int srow = t >> 2;          // staging row within 64-row group
  const int sk   = (t & 3) * 8;     // staging k offset (8 bf16 = 16B)

  auto stage = [&](int buf, int k0) {
    #pragma unroll
    for (int p = 0; p < PA; ++p)
      gload16(&Ab[(long long)(m0 + p * 64 + srow) * lda + k0 + sk],
              &As[buf][p * 2048 + w * 512]);
    #pragma unroll
    for (int p = 0; p < PB; ++p)
      gload16(&Bb[(long long)(n0 + p * 64 + srow) * ldb + k0 + sk],
              &Bs[buf][p * 2048 + w * 512]);
  };

  f32x4 acc[FM][FN] = {};
  stage(0, 0);
  int cur = 0;
  for (int k0 = 0; k0 < K; k0 += 32) {
    __syncthreads();                       // drains stage(cur) (vmcnt0 auto)
    if (k0 + 32 < K) stage(cur ^ 1, k0 + 32);   // prefetch overlaps MFMA below

    bf16x8 af[FM], bfr[FN];
    #pragma unroll
    for (int i = 0; i < FM; ++i)
      af[i] = *reinterpret_cast<const bf16x8*>(
          &As[cur][(wr * SM + i * 16 + (l & 15)) * 32 + (l >> 4) * 8]);
    #pragma unroll
    for (int j = 0; j < FN; ++j)
      bfr[j] = *reinterpret_cast<const bf16x8*>(
          &Bs[cur][(wc * SN + j * 16 + (l & 15)) * 32 + (l >> 4) * 8]);
    #pragma unroll
    for (int i = 0; i < FM; ++i)
      #pragma unroll
      for (int j = 0; j < FN; ++j)
        acc[i][j] = __builtin_amdgcn_mfma_f32_16x16x32_bf16(af[i], bfr[j], acc[i][j], 0, 0, 0);
    cur ^= 1;
  }

  const int c_l = l & 15, r_l4 = (l >> 4) * 4;
  #pragma unroll
  for (int i = 0; i < FM; ++i) {
    #pragma unroll
    for (int r = 0; r < 4; ++r) {
      const long long row = m0 + wr * SM + i * 16 + r_l4 + r;
      #pragma unroll
      for (int j = 0; j < FN; ++j) {
        const int col = n0 + wc * SN + j * 16 + c_l;
        float v = acc[i][j][r] * alpha;
        if (EPI & E_BIAS) v += bias[col];
        if (EPI & E_RES)  v += res[row * (long long)ldc + col];
        if (EPI & E_RELU) v = fmaxf(v, 0.f);
        const long long co = offC + row * (long long)ldc + col;
        if (EPI & E_WF32) C[co] = v;
        if (EPI & E_WB16) Cb[co] = f2b(v);
      }
    }
  }
}

// ---------------------------------------------------------------------------
__global__ __launch_bounds__(256)
void cvt_bf16(const float* __restrict__ in, u16* __restrict__ out)
{
  const long long i = ((long long)blockIdx.x * 256 + threadIdx.x) * 4;
  float4 x = *reinterpret_cast<const float4*>(&in[i]);
  u16x4 o = {f2b(x.x), f2b(x.y), f2b(x.z), f2b(x.w)};
  *reinterpret_cast<u16x4*>(&out[i]) = o;
}

__global__ __launch_bounds__(256)
void cvt_add_bf16(const float* __restrict__ a, const float* __restrict__ b,
                  u16* __restrict__ out)
{
  const long long i = ((long long)blockIdx.x * 256 + threadIdx.x) * 4;
  float4 x = *reinterpret_cast<const float4*>(&a[i]);
  float4 y = *reinterpret_cast<const float4*>(&b[i]);
  u16x4 o = {f2b(x.x + y.x), f2b(x.y + y.y), f2b(x.z + y.z), f2b(x.w + y.w)};
  *reinterpret_cast<u16x4*>(&out[i]) = o;
}

// Transpose u16 [nb][R][C] (row-stride ldin, batch sbin) -> u16 [nb][C][R]
__global__ __launch_bounds__(256)
void transpose_u16(const u16* __restrict__ in, u16* __restrict__ out,
                   int R, int C, int ldin, long long sbin, long long sbout)
{
  __shared__ u16 tile[32][34];
  const int b = blockIdx.z;
  const int r0 = blockIdx.y * 32, c0 = blockIdx.x * 32;
  const int tx = threadIdx.x & 31, ty = threadIdx.x >> 5;
  const u16* ib = in + (long long)b * sbin;
  u16* ob = out + (long long)b * sbout;
  #pragma unroll
  for (int p = 0; p < 4; ++p) {
    int r = ty + p * 8;
    tile[r][tx] = ib[(long long)(r0 + r) * ldin + c0 + tx];
  }
  __syncthreads();
  #pragma unroll
  for (int p = 0; p < 4; ++p) {
    int c = ty + p * 8;
    ob[(long long)(c0 + c) * R + r0 + tx] = tile[tx][c];
  }
}

// ---------------------------------------------------------------------------
// vox f32 [B][NV][D]  ->  vb bf16 [B][NV][D]  AND  vt bf16 [B][D][NV]
// One read of the f32 data produces both bf16 copies. 64x64 tiles.
// ---------------------------------------------------------------------------
__global__ __launch_bounds__(256)
void vox_prep(const float* __restrict__ in, u16* __restrict__ vb,
              u16* __restrict__ vt)
{
  __shared__ u16 tile[64][68];
  const int b = blockIdx.z;
  const int n0 = blockIdx.y * 64;   // NV dim
  const int d0 = blockIdx.x * 64;   // D dim
  const int t = threadIdx.x;
  const int tr = t >> 4;            // 0..15
  const int tc = (t & 15) * 4;      // 0..60
  const float* ib = in + (long long)b * NV * D;
  u16* vbb = vb + (long long)b * NV * D;
  u16* vtb = vt + (long long)b * NV * D;
  #pragma unroll
  for (int p = 0; p < 4; ++p) {
    int r = tr + p * 16;
    float4 x = *reinterpret_cast<const float4*>(&ib[(long long)(n0 + r) * D + d0 + tc]);
    u16x4 o = {f2b(x.x), f2b(x.y), f2b(x.z), f2b(x.w)};
    *reinterpret_cast<u16x4*>(&vbb[(long long)(n0 + r) * D + d0 + tc]) = o;
    *reinterpret_cast<u16x4*>(&tile[r][tc]) = o;
  }
  __syncthreads();
  #pragma unroll
  for (int p = 0; p < 4; ++p) {
    int c = tr + p * 16;            // orig col (d)
    u16x4 o = {tile[tc + 0][c], tile[tc + 1][c], tile[tc + 2][c], tile[tc + 3][c]};
    *reinterpret_cast<u16x4*>(&vtb[(long long)(d0 + c) * NV + n0 + tc]) = o;
  }
}

// ---------------------------------------------------------------------------
__global__ __launch_bounds__(256)
void txt_softmax(const float* __restrict__ sc, const int* __restrict__ mask,
                 u16* __restrict__ wout)
{
  __shared__ float tmp[256];
  const int t = threadIdx.x;
  const int row = blockIdx.x;
  const int b = row >> 12;                      // H*NQ = 4096
  const float* sr = sc + (long long)row * LT;
  u16* wr = wout + (long long)row * LT;
  const int* mr = mask + b * LT;
  float x0 = mr[t]       ? -INFINITY : sr[t];
  float x1 = mr[t + 256] ? -INFINITY : sr[t + 256];
  tmp[t] = fmaxf(x0, x1);
  __syncthreads();
  for (int o = 128; o > 0; o >>= 1) { if (t < o) tmp[t] = fmaxf(tmp[t], tmp[t + o]); __syncthreads(); }
  const float mx = tmp[0];
  __syncthreads();
  float e0 = __expf(x0 - mx), e1 = __expf(x1 - mx);
  tmp[t] = e0 + e1;
  __syncthreads();
  for (int o = 128; o > 0; o >>= 1) { if (t < o) tmp[t] += tmp[t + o]; __syncthreads(); }
  const float inv = 1.f / tmp[0];
  wr[t]       = f2b(e0 * inv);
  wr[t + 256] = f2b(e1 * inv);
}

__global__ __launch_bounds__(256)
void head_mean(const u16* __restrict__ w, float* __restrict__ out1)
{
  const long long idx = (long long)blockIdx.x * 256 + threadIdx.x;  // B*NQ*LT
  const int b = (int)(idx >> 17);               // NQ*LT = 131072
  const long long ql = idx & 131071;
  const u16* p = w + ((long long)b * H) * 131072 + ql;
  float s = 0.f;
  #pragma unroll
  for (int h = 0; h < H; ++h) s += b2f(p[(long long)h * 131072]);
  out1[idx] = s * (1.f / H);
}

// ---------------------------------------------------------------------------
__global__ __launch_bounds__(256)
void ln_kernel(const float* __restrict__ x, const float* __restrict__ g,
               const float* __restrict__ bia, float* __restrict__ y,
               u16* __restrict__ yb, float scale)
{
  __shared__ float tmp[256];
  const int t = threadIdx.x;
  const long long off = (long long)blockIdx.x * D;
  float4 x4 = *reinterpret_cast<const float4*>(&x[off + t * 4]);
  tmp[t] = x4.x + x4.y + x4.z + x4.w;
  __syncthreads();
  for (int o = 128; o > 0; o >>= 1) { if (t < o) tmp[t] += tmp[t + o]; __syncthreads(); }
  const float mean = tmp[0] * (1.f / D);
  __syncthreads();
  float d0 = x4.x - mean, d1 = x4.y - mean, d2 = x4.z - mean, d3 = x4.w - mean;
  tmp[t] = d0 * d0 + d1 * d1 + d2 * d2 + d3 * d3;
  __syncthreads();
  for (int o = 128; o > 0; o >>= 1) { if (t < o) tmp[t] += tmp[t + o]; __syncthreads(); }
  const float rs = rsqrtf(tmp[0] * (1.f / D) + 1e-5f);
  float4 g4 = *reinterpret_cast<const float4*>(&g[t * 4]);
  float4 b4 = *reinterpret_cast<const float4*>(&bia[t * 4]);
  float o0 = (d0 * rs * g4.x + b4.x) * scale;
  float o1 = (d1 * rs * g4.y + b4.y) * scale;
  float o2 = (d2 * rs * g4.z + b4.z) * scale;
  float o3 = (d3 * rs * g4.w + b4.w) * scale;
  if (y) {
    float4 o4 = {o0, o1, o2, o3};
    *reinterpret_cast<float4*>(&y[off + t * 4]) = o4;
  }
  if (yb) {
    u16x4 ob = {f2b(o0), f2b(o1), f2b(o2), f2b(o3)};
    *reinterpret_cast<u16x4*>(&yb[off + t * 4]) = ob;
  }
}

// ---------------------------------------------------------------------------
__global__ __launch_bounds__(256)
void vox_softmax(float* __restrict__ s, const int* __restrict__ mask,
                 u16* __restrict__ wb)
{
  __shared__ float tmp[256];
  const int t = threadIdx.x;
  const int row = blockIdx.x, b = row / NQ;
  float* sr = s + (long long)row * NV;
  u16* wr = wb + (long long)row * NV;
  const int* mr = mask + b * NV;
  float vals[16];
  float lm = -INFINITY;
  #pragma unroll
  for (int j = 0; j < 16; ++j) {
    int n = t + j * 256;
    float x = mr[n] ? -INFINITY : sr[n];
    vals[j] = x;
    lm = fmaxf(lm, x);
  }
  tmp[t] = lm;
  __syncthreads();
  for (int o = 128; o > 0; o >>= 1) { if (t < o) tmp[t] = fmaxf(tmp[t], tmp[t + o]); __syncthreads(); }
  const float mx = tmp[0];
  __syncthreads();
  float ls = 0.f;
  #pragma unroll
  for (int j = 0; j < 16; ++j) { vals[j] = __expf(vals[j] - mx); ls += vals[j]; }
  tmp[t] = ls;
  __syncthreads();
  for (int o = 128; o > 0; o >>= 1) { if (t < o) tmp[t] += tmp[t + o]; __syncthreads(); }
  const float inv = 1.f / tmp[0];
  #pragma unroll
  for (int j = 0; j < 16; ++j) {
    float v = vals[j] * inv;
    sr[t + j * 256] = v;
    wr[t + j * 256] = f2b(v);
  }
}

// split-K reduce: out[b][o] = sum_{p<4} part[b][p][o]
__global__ __launch_bounds__(256)
void splitk_reduce(const float* __restrict__ part, float* __restrict__ out)
{
  const long long i = ((long long)blockIdx.x * 256 + threadIdx.x) * 4;
  const long long nd = (long long)NQ * D;
  const long long b = i / nd;
  const long long o = i - b * nd;
  const float* p = part + b * 4 * nd + o;
  float4 s0 = *reinterpret_cast<const float4*>(&p[0]);
  float4 s1 = *reinterpret_cast<const float4*>(&p[nd]);
  float4 s2 = *reinterpret_cast<const float4*>(&p[2 * nd]);
  float4 s3 = *reinterpret_cast<const float4*>(&p[3 * nd]);
  float4 r = {s0.x + s1.x + s2.x + s3.x, s0.y + s1.y + s2.y + s3.y,
              s0.z + s1.z + s2.z + s3.z, s0.w + s1.w + s2.w + s3.w};
  *reinterpret_cast<float4*>(&out[i]) = r;
}

// ---------------------------------------------------------------------------
extern "C" void kernel_launch(void* const* d_in, const int* in_sizes, int n_in,
                              void* d_out, int out_size, void* d_ws, size_t ws_size,
                              hipStream_t stream)
{
  const float* tgt   = (const float*)d_in[0];
  const float* mtxt  = (const float*)d_in[1];
  const float* vox   = (const float*)d_in[2];
  const float* qpos  = (const float*)d_in[3];
  const int*   mtx_m = (const int*)d_in[4];
  const int*   vox_m = (const int*)d_in[5];
  const float* Wq = (const float*)d_in[6];  const float* bq = (const float*)d_in[7];
  const float* Wk = (const float*)d_in[8];  const float* bk = (const float*)d_in[9];
  const float* Wv = (const float*)d_in[10]; const float* bv = (const float*)d_in[11];
  const float* Wo = (const float*)d_in[12]; const float* bo = (const float*)d_in[13];
  const float* W1 = (const float*)d_in[14]; const float* b1 = (const float*)d_in[15];
  const float* W2 = (const float*)d_in[16]; const float* b2 = (const float*)d_in[17];
  const float* ln1g = (const float*)d_in[18]; const float* ln1b = (const float*)d_in[19];
  const float* ln2g = (const float*)d_in[20]; const float* ln2b = (const float*)d_in[21];

  float* out0 = (float*)d_out;                       // attn_output  [B,NQ,D]
  float* out1 = out0 + (long long)B * NQ * D;        // txt_cross    [B,NQ,LT]
  float* out2 = out1 + (long long)B * NQ * LT;       // attn_weights [B,NQ,NV]

  // --- workspace layout (MiB offsets). Peak = 232 MiB. ---
  char* base = (char*)d_ws;
  constexpr size_t MB = 1ull << 20;
  u16*   kvW   = (u16*)(base + 0 * MB);     // 16  [Wk;Wv] stacked [2048][4096]
  u16*   Wq_b  = (u16*)(base + 16 * MB);    // 2
  u16*   Wo_b  = (u16*)(base + 18 * MB);    // 2
  u16*   W1_b  = (u16*)(base + 20 * MB);    // 4
  u16*   W2_b  = (u16*)(base + 24 * MB);    // 4
  u16*   tq_b  = (u16*)(base + 28 * MB);    // 4
  u16*   q_b   = (u16*)(base + 32 * MB);    // 4
  u16*   kv_b  = (u16*)(base + 36 * MB);    // 16  [B*LT][2048] (k | v)
  u16*   vT_b  = (u16*)(base + 52 * MB);    // 8   [B][D][LT]
  u16*   ctx_b = (u16*)(base + 60 * MB);    // 4
  float* x1p   = (float*)(base + 64 * MB);  // 8
  float* x1f   = (float*)(base + 72 * MB);  // 8
  u16*   x1_b  = (u16*)(base + 80 * MB);    // 4
  u16*   ff1_b = (u16*)(base + 84 * MB);    // 8
  float* x2p   = (float*)(base + 92 * MB);  // 8
  u16*   x2s_b = (u16*)(base + 100 * MB);   // 4
  u16*   mtxt_b = (u16*)(base + 104 * MB);  // 32  dead after KV proj
  float* scores = (float*)(base + 136 * MB);// 64  dead after txt_softmax
  u16*   w_b    = (u16*)(base + 200 * MB);  // 32  dead after ctx gemm
  float* bkv    = (float*)(base + 136 * MB);// 8KB, dead before scores written
  u16*   vox_b  = (u16*)(base + 104 * MB);  // 64  overlays mtxt+scores head
  u16*   voxT_b = (u16*)(base + 168 * MB);  // 64  overlays scores tail+w_b
  u16*   wvox_b = (u16*)(base + 0 * MB);    // 16  overlays kvW (dead)
  float* part   = (float*)(base + 16 * MB); // 32  overlays Wq..kv_b head (dead)

  const dim3 blk(256);
  const long long sQ = (long long)NQ * D;      // 262144
  const long long sSC = (long long)NQ * LT;    // 131072
  const long long nd = (long long)NQ * D;

  // 1) weight/input conversions
  cvt_bf16<<<dim3((D * D) / 1024), blk, 0, stream>>>(Wq, Wq_b);
  cvt_bf16<<<dim3((D * FTXT) / 1024), blk, 0, stream>>>(Wk, kvW);
  cvt_bf16<<<dim3((D * FTXT) / 1024), blk, 0, stream>>>(Wv, kvW + (long long)D * FTXT);
  cvt_bf16<<<dim3((D * D) / 1024), blk, 0, stream>>>(Wo, Wo_b);
  cvt_bf16<<<dim3((DFF * D) / 1024), blk, 0, stream>>>(W1, W1_b);
  cvt_bf16<<<dim3((D * DFF) / 1024), blk, 0, stream>>>(W2, W2_b);
  hipMemcpyAsync(bkv, bk, D * sizeof(float), hipMemcpyDeviceToDevice, stream);
  hipMemcpyAsync(bkv + D, bv, D * sizeof(float), hipMemcpyDeviceToDevice, stream);
  cvt_add_bf16<<<dim3((B * NQ * D) / 1024), blk, 0, stream>>>(tgt, qpos, tq_b);
  cvt_bf16<<<dim3((B * LT * FTXT) / 1024), blk, 0, stream>>>(mtxt, mtxt_b);

  // 2) q = tq @ Wq^T + bq  (256 blocks)
  gemm_bf16<128,64,2,2, E_BIAS|E_WB16><<<dim3(D/64, (B*NQ)/128, 1), blk, 0, stream>>>(
      tq_b, Wq_b, bq, nullptr, nullptr, q_b, D, D, D, D, 1, 0,0,0,0,0,0, 1.f);
  //    kv = mtxt @ [Wk;Wv]^T + [bk;bv]  (512 blocks)
  gemm_bf16<128,128,2,2, E_BIAS|E_WB16><<<dim3(2048/128, (B*LT)/128, 1), blk, 0, stream>>>(
      mtxt_b, kvW, bkv, nullptr, nullptr, kv_b, FTXT, FTXT, FTXT, 2048, 1,
      0,0,0,0,0,0, 1.f);

  // 3) vT[b][d][l] = v[b][l][d]  (v = kv_b cols 1024..2047)
  transpose_u16<<<dim3(D/32, LT/32, B), blk, 0, stream>>>(
      kv_b + 1024, vT_b, LT, D, 2048, (long long)LT * 2048, (long long)D * LT);

  // 4) scores[b,h,q,l] = (q_h . k_h) / 8   (1024 blocks)
  gemm_bf16<128,128,2,2, E_WF32><<<dim3(LT/128, NQ/128, B*H), blk, 0, stream>>>(
      q_b, kv_b, nullptr, nullptr, scores, nullptr, HD, D, 2048, LT, H,
      sQ, HD, (long long)LT * 2048, HD, (long long)H * sSC, sSC, 0.125f);

  // 5) softmax -> w bf16 ; out1 = head mean
  txt_softmax<<<dim3(B*H*NQ), blk, 0, stream>>>(scores, mtx_m, w_b);
  head_mean<<<dim3((B*NQ*LT)/256), blk, 0, stream>>>(w_b, out1);

  // 6) ctx = w_h @ v_h  (512 blocks)
  gemm_bf16<64,64,2,2, E_WB16><<<dim3(HD/64, NQ/64, B*H), blk, 0, stream>>>(
      w_b, vT_b, nullptr, nullptr, nullptr, ctx_b, LT, LT, LT, D, H,
      (long long)H * sSC, sSC, (long long)D * LT, (long long)HD * LT, sQ, HD, 1.f);

  // 7) vox -> vox_b (bf16) + voxT_b (bf16 transposed), one read
  vox_prep<<<dim3(D/64, NV/64, B), blk, 0, stream>>>(vox, vox_b, voxT_b);

  // 8) x1p = tgt + ctx @ Wo^T + bo  (512 blocks)
  gemm_bf16<64,64,2,2, E_BIAS|E_RES|E_WF32><<<dim3(D/64, (B*NQ)/64, 1), blk, 0, stream>>>(
      ctx_b, Wo_b, bo, tgt, x1p, nullptr, D, D, D, D, 1, 0,0,0,0,0,0, 1.f);

  // 9) LN1 -> x1 (f32 + bf16)
  ln_kernel<<<dim3(B*NQ), blk, 0, stream>>>(x1p, ln1g, ln1b, x1f, x1_b, 1.f);

  // 10) ff1 = relu(x1 @ W1^T + b1)  (512 blocks)
  gemm_bf16<128,64,2,2, E_BIAS|E_RELU|E_WB16><<<dim3(DFF/64, (B*NQ)/128, 1), blk, 0, stream>>>(
      x1_b, W1_b, b1, nullptr, nullptr, ff1_b, D, D, D, DFF, 1, 0,0,0,0,0,0, 1.f);

  // 11) x2p = x1 + ff1 @ W2^T + b2  (512 blocks)
  gemm_bf16<64,64,2,2, E_BIAS|E_RES|E_WF32><<<dim3(D/64, (B*NQ)/64, 1), blk, 0, stream>>>(
      ff1_b, W2_b, b2, x1f, x2p, nullptr, DFF, DFF, DFF, D, 1, 0,0,0,0,0,0, 1.f);

  // 12) LN2 -> x2s (bf16, /sqrt(D))
  ln_kernel<<<dim3(B*NQ), blk, 0, stream>>>(x2p, ln2g, ln2b, nullptr, x2s_b, 0.03125f);

  // 13) out2 = x2s @ vox^T  (512 blocks)
  gemm_bf16<128,128,2,2, E_WF32><<<dim3(NV/128, NQ/128, B), blk, 0, stream>>>(
      x2s_b, vox_b, nullptr, nullptr, out2, nullptr, D, D, D, NV, 1,
      sQ, 0, (long long)NV * D, 0, (long long)NQ * NV, 0, 1.f);

  // 14) masked softmax in place; bf16 weights
  vox_softmax<<<dim3(B*NQ), blk, 0, stream>>>(out2, vox_m, wvox_b);

  // 15) out0 partials: split-K=4 over NV (512 blocks), then reduce
  gemm_bf16<128,128,2,2, E_WF32><<<dim3(D/128, NQ/128, B*4), blk, 0, stream>>>(
      wvox_b, voxT_b, nullptr, nullptr, part, nullptr, NV/4, NV, NV, D, 4,
      (long long)NQ * NV, 1024, (long long)D * NV, 1024, 4 * nd, nd, 1.f);
  splitk_reduce<<<dim3((B * NQ * D) / 1024), blk, 0, stream>>>(part, out0);
}

// Round 4
// 476.302 us; speedup vs baseline: 5.1150x; 1.0204x over previous
//
#include <hip/hip_runtime.h>
#include <math.h>

typedef unsigned short u16;
typedef unsigned int u32;
typedef __bf16 bf16x8 __attribute__((ext_vector_type(8)));
typedef float f32x4 __attribute__((ext_vector_type(4)));
typedef u16 u16x4 __attribute__((ext_vector_type(4)));

constexpr int B = 8, NQ = 256, LT = 512, NV = 4096;
constexpr int D = 1024, H = 16, DFF = 2048, FTXT = 4096, HD = 64;

__device__ __forceinline__ u16 f2b(float f) {
  u32 u = __builtin_bit_cast(u32, f);
  return (u16)((u + 0x7fffu + ((u >> 16) & 1u)) >> 16);   // RNE
}
__device__ __forceinline__ float b2f(u16 b) {
  u32 u = ((u32)b) << 16;
  return __builtin_bit_cast(float, u);
}
__device__ __forceinline__ void gload16(const void* g, void* l) {
  __builtin_amdgcn_global_load_lds(
      (const __attribute__((address_space(1))) u32*)g,
      (__attribute__((address_space(3))) u32*)l, 16, 0, 0);
}

// ---------------------------------------------------------------------------
// bf16 MFMA GEMM: C[M,N] = alpha * A[M,K] @ B^T (+bias)(+res)(relu?)
// BSRC: 0 = B is bf16 [N][K] via global_load_lds
//       1 = B is f32  [N][K], reg-staged + cvt (BN must be 128)
//       2 = B is f32  [K][N], reg-staged + cvt + transpose  (BN must be 128)
// 2-phase double-buffered staging; for BSRC!=0 the global loads are issued
// BEFORE the MFMA phase and the LDS writes after it (T14 split).
// XCD-bijective block swizzle (m204). Batched via bz=(bz/nbz2, bz%nbz2).
// ---------------------------------------------------------------------------
constexpr int E_BIAS = 1, E_RES = 2, E_RELU = 4, E_WF32 = 8, E_WB16 = 16;

template<int BM, int BN, int WM, int WN, int EPI, int BSRC>
__global__ __launch_bounds__(256)
void gemm_bf16(const u16* __restrict__ A, const void* __restrict__ Bw,
               const float* __restrict__ bias, const float* __restrict__ res,
               float* __restrict__ C, u16* __restrict__ Cb,
               int K, int lda, int ldb, int ldc, int nbz2,
               long long sA1, long long sA2, long long sB1, long long sB2,
               long long sC1, long long sC2, float alpha)
{
  static_assert(BSRC == 0 || BN == 128, "reg-staged B assumes BN=128");
  constexpr int SM = BM / WM, SN = BN / WN;
  constexpr int FM = SM / 16, FN = SN / 16;
  constexpr int PA = BM / 64, PB = BN / 64;
  __shared__ __align__(16) u16 As[2][BM * 32];
  __shared__ __align__(16) u16 Bs[2][BN * 32];

  // XCD-aware bijective swizzle over the flattened grid
  const int gx = gridDim.x, gy = gridDim.y;
  const int nwg = gx * gy * gridDim.z;
  const int flat = (blockIdx.z * gy + blockIdx.y) * gx + blockIdx.x;
  const int qq = nwg >> 3, rr = nwg & 7;
  const int xcd = flat & 7, lid = flat >> 3;
  const int wg = (xcd < rr ? xcd * (qq + 1) : rr * (qq + 1) + (xcd - rr) * qq) + lid;
  const int bx = wg % gx;
  const int tmp1 = wg / gx;
  const int by = tmp1 % gy, bz = tmp1 / gy;

  const int t = threadIdx.x;
  const int w = t >> 6, l = t & 63;
  const int wr = w / WN, wc = w % WN;
  const int m0 = by * BM, n0 = bx * BN;
  const long long offA = (long long)(bz / nbz2) * sA1 + (long long)(bz % nbz2) * sA2;
  const long long offB = (long long)(bz / nbz2) * sB1 + (long long)(bz % nbz2) * sB2;
  const long long offC = (long long)(bz / nbz2) * sC1 + (long long)(bz % nbz2) * sC2;
  const u16* Ab = A + offA;

  const int srow = t >> 2;          // staging row within 64-row group
  const int sk   = (t & 3) * 8;     // staging k offset (8 bf16 = 16B)

  auto stageA = [&](int buf, int k0) {
    #pragma unroll
    for (int p = 0; p < PA; ++p)
      gload16(&Ab[(long long)(m0 + p * 64 + srow) * lda + k0 + sk],
              &As[buf][p * 2048 + w * 512]);
  };
  auto stageB_g = [&](int buf, int k0) {
    const u16* Bb = (const u16*)Bw + offB;
    #pragma unroll
    for (int p = 0; p < PB; ++p)
      gload16(&Bb[(long long)(n0 + p * 64 + srow) * ldb + k0 + sk],
              &Bs[buf][p * 2048 + w * 512]);
  };
  auto loadB = [&](float4* rg, int k0) {
    const float* Bf = (const float*)Bw + offB;
    if constexpr (BSRC == 1) {
      const int r = t >> 1, c0 = (t & 1) * 16;
      #pragma unroll
      for (int c = 0; c < 4; ++c)
        rg[c] = *reinterpret_cast<const float4*>(
            &Bf[(long long)(n0 + r) * ldb + k0 + c0 + c * 4]);
    } else {
      const int kk = t >> 3;
      #pragma unroll
      for (int p = 0; p < 4; ++p)
        rg[p] = *reinterpret_cast<const float4*>(
            &Bf[(long long)(k0 + kk) * ldb + n0 + (t & 7) * 4 + 32 * p]);
    }
  };
  auto writeB = [&](int buf, const float4* rg) {
    if constexpr (BSRC == 1) {
      const int r = t >> 1, c0 = (t & 1) * 16;
      #pragma unroll
      for (int c = 0; c < 4; ++c) {
        u16x4 o = {f2b(rg[c].x), f2b(rg[c].y), f2b(rg[c].z), f2b(rg[c].w)};
        *reinterpret_cast<u16x4*>(&Bs[buf][r * 32 + c0 + c * 4]) = o;
      }
    } else {
      const int kk = t >> 3;
      #pragma unroll
      for (int p = 0; p < 4; ++p) {
        const int nn = (t & 7) * 4 + 32 * p;
        Bs[buf][(nn + 0) * 32 + kk] = f2b(rg[p].x);
        Bs[buf][(nn + 1) * 32 + kk] = f2b(rg[p].y);
        Bs[buf][(nn + 2) * 32 + kk] = f2b(rg[p].z);
        Bs[buf][(nn + 3) * 32 + kk] = f2b(rg[p].w);
      }
    }
  };

  f32x4 acc[FM][FN] = {};

  // prologue: stage tile 0 (immediate)
  stageA(0, 0);
  if constexpr (BSRC == 0) {
    stageB_g(0, 0);
  } else {
    float4 rg[4];
    loadB(rg, 0);
    writeB(0, rg);
  }

  int cur = 0;
  for (int k0 = 0; k0 < K; k0 += 32) {
    __syncthreads();                       // buf cur ready; buf cur^1 free
    const bool pf = (k0 + 32 < K);
    float4 rg[4];
    if (pf) {
      stageA(cur ^ 1, k0 + 32);            // async gload16
      if constexpr (BSRC == 0) stageB_g(cur ^ 1, k0 + 32);
      else                     loadB(rg, k0 + 32);   // issue loads, no wait
    }

    bf16x8 af[FM], bfr[FN];
    #pragma unroll
    for (int i = 0; i < FM; ++i)
      af[i] = *reinterpret_cast<const bf16x8*>(
          &As[cur][(wr * SM + i * 16 + (l & 15)) * 32 + (l >> 4) * 8]);
    #pragma unroll
    for (int j = 0; j < FN; ++j)
      bfr[j] = *reinterpret_cast<const bf16x8*>(
          &Bs[cur][(wc * SN + j * 16 + (l & 15)) * 32 + (l >> 4) * 8]);
    #pragma unroll
    for (int i = 0; i < FM; ++i)
      #pragma unroll
      for (int j = 0; j < FN; ++j)
        acc[i][j] = __builtin_amdgcn_mfma_f32_16x16x32_bf16(af[i], bfr[j], acc[i][j], 0, 0, 0);

    if constexpr (BSRC != 0) {
      if (pf) writeB(cur ^ 1, rg);         // cvt+ds_write; loads landed under MFMA
    }
    cur ^= 1;
  }

  const int c_l = l & 15, r_l4 = (l >> 4) * 4;
  #pragma unroll
  for (int i = 0; i < FM; ++i) {
    #pragma unroll
    for (int r = 0; r < 4; ++r) {
      const long long row = m0 + wr * SM + i * 16 + r_l4 + r;
      #pragma unroll
      for (int j = 0; j < FN; ++j) {
        const int col = n0 + wc * SN + j * 16 + c_l;
        float v = acc[i][j][r] * alpha;
        if (EPI & E_BIAS) v += bias[col];
        if (EPI & E_RES)  v += res[row * (long long)ldc + col];
        if (EPI & E_RELU) v = fmaxf(v, 0.f);
        const long long co = offC + row * (long long)ldc + col;
        if (EPI & E_WF32) C[co] = v;
        if (EPI & E_WB16) Cb[co] = f2b(v);
      }
    }
  }
}

// ---------------------------------------------------------------------------
__global__ __launch_bounds__(256)
void cvt_bf16(const float* __restrict__ in, u16* __restrict__ out)
{
  const long long i = ((long long)blockIdx.x * 256 + threadIdx.x) * 4;
  float4 x = *reinterpret_cast<const float4*>(&in[i]);
  u16x4 o = {f2b(x.x), f2b(x.y), f2b(x.z), f2b(x.w)};
  *reinterpret_cast<u16x4*>(&out[i]) = o;
}

__global__ __launch_bounds__(256)
void cvt_add_bf16(const float* __restrict__ a, const float* __restrict__ b,
                  u16* __restrict__ out)
{
  const long long i = ((long long)blockIdx.x * 256 + threadIdx.x) * 4;
  float4 x = *reinterpret_cast<const float4*>(&a[i]);
  float4 y = *reinterpret_cast<const float4*>(&b[i]);
  u16x4 o = {f2b(x.x + y.x), f2b(x.y + y.y), f2b(x.z + y.z), f2b(x.w + y.w)};
  *reinterpret_cast<u16x4*>(&out[i]) = o;
}

// Transpose u16 [nb][R][C] (row-stride ldin, batch sbin) -> u16 [nb][C][R]
__global__ __launch_bounds__(256)
void transpose_u16(const u16* __restrict__ in, u16* __restrict__ out,
                   int R, int C, int ldin, long long sbin, long long sbout)
{
  __shared__ u16 tile[32][34];
  const int b = blockIdx.z;
  const int r0 = blockIdx.y * 32, c0 = blockIdx.x * 32;
  const int tx = threadIdx.x & 31, ty = threadIdx.x >> 5;
  const u16* ib = in + (long long)b * sbin;
  u16* ob = out + (long long)b * sbout;
  #pragma unroll
  for (int p = 0; p < 4; ++p) {
    int r = ty + p * 8;
    tile[r][tx] = ib[(long long)(r0 + r) * ldin + c0 + tx];
  }
  __syncthreads();
  #pragma unroll
  for (int p = 0; p < 4; ++p) {
    int c = ty + p * 8;
    ob[(long long)(c0 + c) * R + r0 + tx] = tile[tx][c];
  }
}

// ---------------------------------------------------------------------------
// Fused masked softmax (rows of LT=512) + head-mean. One block per (b,q);
// loops over the 16 heads, writes w bf16 and out1[b,q,:] = mean_h w.
// ---------------------------------------------------------------------------
__global__ __launch_bounds__(256)
void txt_softmax_mean(const float* __restrict__ sc, const int* __restrict__ mask,
                      u16* __restrict__ wout, float* __restrict__ out1)
{
  __shared__ float red[8];
  const int t = threadIdx.x, l = t & 63, w = t >> 6;
  const int bq = blockIdx.x;
  const int b = bq >> 8, q = bq & 255;
  const int* mr = mask + b * LT;
  const bool msk0 = mr[t] != 0, msk1 = mr[t + 256] != 0;
  float a0 = 0.f, a1 = 0.f;
  for (int h = 0; h < H; ++h) {
    const long long ro = (((long long)(b * H + h)) * NQ + q) * LT;
    const float* sr = sc + ro;
    float x0 = msk0 ? -INFINITY : sr[t];
    float x1 = msk1 ? -INFINITY : sr[t + 256];
    float mx = fmaxf(x0, x1);
    #pragma unroll
    for (int o = 32; o > 0; o >>= 1) mx = fmaxf(mx, __shfl_xor(mx, o, 64));
    if (l == 0) red[w] = mx;
    __syncthreads();
    mx = fmaxf(fmaxf(red[0], red[1]), fmaxf(red[2], red[3]));
    float e0 = __expf(x0 - mx), e1 = __expf(x1 - mx);
    float s = e0 + e1;
    #pragma unroll
    for (int o = 32; o > 0; o >>= 1) s += __shfl_xor(s, o, 64);
    if (l == 0) red[4 + w] = s;
    __syncthreads();
    s = red[4] + red[5] + red[6] + red[7];
    const float inv = 1.f / s;
    const float w0 = e0 * inv, w1 = e1 * inv;
    u16* wr = wout + ro;
    wr[t] = f2b(w0); wr[t + 256] = f2b(w1);
    a0 += w0; a1 += w1;
  }
  float* o1 = out1 + (long long)bq * LT;
  o1[t]       = a0 * (1.f / H);
  o1[t + 256] = a1 * (1.f / H);
}

// ---------------------------------------------------------------------------
__global__ __launch_bounds__(256)
void ln_kernel(const float* __restrict__ x, const float* __restrict__ g,
               const float* __restrict__ bia, float* __restrict__ y,
               u16* __restrict__ yb, float scale)
{
  __shared__ float tmp[256];
  const int t = threadIdx.x;
  const long long off = (long long)blockIdx.x * D;
  float4 x4 = *reinterpret_cast<const float4*>(&x[off + t * 4]);
  tmp[t] = x4.x + x4.y + x4.z + x4.w;
  __syncthreads();
  for (int o = 128; o > 0; o >>= 1) { if (t < o) tmp[t] += tmp[t + o]; __syncthreads(); }
  const float mean = tmp[0] * (1.f / D);
  __syncthreads();
  float d0 = x4.x - mean, d1 = x4.y - mean, d2 = x4.z - mean, d3 = x4.w - mean;
  tmp[t] = d0 * d0 + d1 * d1 + d2 * d2 + d3 * d3;
  __syncthreads();
  for (int o = 128; o > 0; o >>= 1) { if (t < o) tmp[t] += tmp[t + o]; __syncthreads(); }
  const float rs = rsqrtf(tmp[0] * (1.f / D) + 1e-5f);
  float4 g4 = *reinterpret_cast<const float4*>(&g[t * 4]);
  float4 b4 = *reinterpret_cast<const float4*>(&bia[t * 4]);
  float o0 = (d0 * rs * g4.x + b4.x) * scale;
  float o1 = (d1 * rs * g4.y + b4.y) * scale;
  float o2 = (d2 * rs * g4.z + b4.z) * scale;
  float o3 = (d3 * rs * g4.w + b4.w) * scale;
  if (y) {
    float4 o4 = {o0, o1, o2, o3};
    *reinterpret_cast<float4*>(&y[off + t * 4]) = o4;
  }
  if (yb) {
    u16x4 ob = {f2b(o0), f2b(o1), f2b(o2), f2b(o3)};
    *reinterpret_cast<u16x4*>(&yb[off + t * 4]) = ob;
  }
}

// ---------------------------------------------------------------------------
__global__ __launch_bounds__(256)
void vox_softmax(float* __restrict__ s, const int* __restrict__ mask,
                 u16* __restrict__ wb)
{
  __shared__ float tmp[256];
  const int t = threadIdx.x;
  const int row = blockIdx.x, b = row / NQ;
  float* sr = s + (long long)row * NV;
  u16* wr = wb + (long long)row * NV;
  const int* mr = mask + b * NV;
  float vals[16];
  float lm = -INFINITY;
  #pragma unroll
  for (int j = 0; j < 16; ++j) {
    int n = t + j * 256;
    float x = mr[n] ? -INFINITY : sr[n];
    vals[j] = x;
    lm = fmaxf(lm, x);
  }
  tmp[t] = lm;
  __syncthreads();
  for (int o = 128; o > 0; o >>= 1) { if (t < o) tmp[t] = fmaxf(tmp[t], tmp[t + o]); __syncthreads(); }
  const float mx = tmp[0];
  __syncthreads();
  float ls = 0.f;
  #pragma unroll
  for (int j = 0; j < 16; ++j) { vals[j] = __expf(vals[j] - mx); ls += vals[j]; }
  tmp[t] = ls;
  __syncthreads();
  for (int o = 128; o > 0; o >>= 1) { if (t < o) tmp[t] += tmp[t + o]; __syncthreads(); }
  const float inv = 1.f / tmp[0];
  #pragma unroll
  for (int j = 0; j < 16; ++j) {
    float v = vals[j] * inv;
    sr[t + j * 256] = v;
    wr[t + j * 256] = f2b(v);
  }
}

// split-K reduce: out[b][o] = sum_{p<4} part[b][p][o]
__global__ __launch_bounds__(256)
void splitk_reduce(const float* __restrict__ part, float* __restrict__ out)
{
  const long long i = ((long long)blockIdx.x * 256 + threadIdx.x) * 4;
  const long long nd = (long long)NQ * D;
  const long long b = i / nd;
  const long long o = i - b * nd;
  const float* p = part + b * 4 * nd + o;
  float4 s0 = *reinterpret_cast<const float4*>(&p[0]);
  float4 s1 = *reinterpret_cast<const float4*>(&p[nd]);
  float4 s2 = *reinterpret_cast<const float4*>(&p[2 * nd]);
  float4 s3 = *reinterpret_cast<const float4*>(&p[3 * nd]);
  float4 r = {s0.x + s1.x + s2.x + s3.x, s0.y + s1.y + s2.y + s3.y,
              s0.z + s1.z + s2.z + s3.z, s0.w + s1.w + s2.w + s3.w};
  *reinterpret_cast<float4*>(&out[i]) = r;
}

// ---------------------------------------------------------------------------
extern "C" void kernel_launch(void* const* d_in, const int* in_sizes, int n_in,
                              void* d_out, int out_size, void* d_ws, size_t ws_size,
                              hipStream_t stream)
{
  const float* tgt   = (const float*)d_in[0];
  const float* mtxt  = (const float*)d_in[1];
  const float* vox   = (const float*)d_in[2];
  const float* qpos  = (const float*)d_in[3];
  const int*   mtx_m = (const int*)d_in[4];
  const int*   vox_m = (const int*)d_in[5];
  const float* Wq = (const float*)d_in[6];  const float* bq = (const float*)d_in[7];
  const float* Wk = (const float*)d_in[8];  const float* bk = (const float*)d_in[9];
  const float* Wv = (const float*)d_in[10]; const float* bv = (const float*)d_in[11];
  const float* Wo = (const float*)d_in[12]; const float* bo = (const float*)d_in[13];
  const float* W1 = (const float*)d_in[14]; const float* b1 = (const float*)d_in[15];
  const float* W2 = (const float*)d_in[16]; const float* b2 = (const float*)d_in[17];
  const float* ln1g = (const float*)d_in[18]; const float* ln1b = (const float*)d_in[19];
  const float* ln2g = (const float*)d_in[20]; const float* ln2b = (const float*)d_in[21];

  float* out0 = (float*)d_out;                       // attn_output  [B,NQ,D]
  float* out1 = out0 + (long long)B * NQ * D;        // txt_cross    [B,NQ,LT]
  float* out2 = out1 + (long long)B * NQ * LT;       // attn_weights [B,NQ,NV]

  // --- workspace layout (MiB offsets). Peak = 232 MiB. ---
  char* base = (char*)d_ws;
  constexpr size_t MB = 1ull << 20;
  u16*   kvW   = (u16*)(base + 0 * MB);     // 16  [Wk;Wv] stacked [2048][4096]
  u16*   Wq_b  = (u16*)(base + 16 * MB);    // 2
  u16*   Wo_b  = (u16*)(base + 18 * MB);    // 2
  u16*   W1_b  = (u16*)(base + 20 * MB);    // 4
  u16*   W2_b  = (u16*)(base + 24 * MB);    // 4
  u16*   tq_b  = (u16*)(base + 28 * MB);    // 4
  u16*   q_b   = (u16*)(base + 32 * MB);    // 4
  u16*   kv_b  = (u16*)(base + 36 * MB);    // 16  [B*LT][2048] (k | v)
  u16*   vT_b  = (u16*)(base + 52 * MB);    // 8   [B][D][LT]
  u16*   ctx_b = (u16*)(base + 60 * MB);    // 4
  float* x1p   = (float*)(base + 64 * MB);  // 8
  float* x1f   = (float*)(base + 72 * MB);  // 8
  u16*   x1_b  = (u16*)(base + 80 * MB);    // 4
  u16*   ff1_b = (u16*)(base + 84 * MB);    // 8
  float* x2p   = (float*)(base + 92 * MB);  // 8
  u16*   x2s_b = (u16*)(base + 100 * MB);   // 4
  u16*   mtxt_b = (u16*)(base + 104 * MB);  // 32  dead after KV proj
  float* scores = (float*)(base + 136 * MB);// 64  dead after txt_softmax_mean
  u16*   w_b    = (u16*)(base + 200 * MB);  // 32  dead after ctx gemm
  float* bkv    = (float*)(base + 136 * MB);// 8KB, dead before scores written
  u16*   wvox_b = (u16*)(base + 0 * MB);    // 16  overlays kvW (dead)
  float* part   = (float*)(base + 16 * MB); // 32  overlays Wq..kv_b head (dead)

  const dim3 blk(256);
  const long long sQ = (long long)NQ * D;      // 262144
  const long long sSC = (long long)NQ * LT;    // 131072
  const long long nd = (long long)NQ * D;

  // 1) weight/input conversions
  cvt_bf16<<<dim3((D * D) / 1024), blk, 0, stream>>>(Wq, Wq_b);
  cvt_bf16<<<dim3((D * FTXT) / 1024), blk, 0, stream>>>(Wk, kvW);
  cvt_bf16<<<dim3((D * FTXT) / 1024), blk, 0, stream>>>(Wv, kvW + (long long)D * FTXT);
  cvt_bf16<<<dim3((D * D) / 1024), blk, 0, stream>>>(Wo, Wo_b);
  cvt_bf16<<<dim3((DFF * D) / 1024), blk, 0, stream>>>(W1, W1_b);
  cvt_bf16<<<dim3((D * DFF) / 1024), blk, 0, stream>>>(W2, W2_b);
  hipMemcpyAsync(bkv, bk, D * sizeof(float), hipMemcpyDeviceToDevice, stream);
  hipMemcpyAsync(bkv + D, bv, D * sizeof(float), hipMemcpyDeviceToDevice, stream);
  cvt_add_bf16<<<dim3((B * NQ * D) / 1024), blk, 0, stream>>>(tgt, qpos, tq_b);
  cvt_bf16<<<dim3((B * LT * FTXT) / 1024), blk, 0, stream>>>(mtxt, mtxt_b);

  // 2) q = tq @ Wq^T + bq  (512 blocks)
  gemm_bf16<64,64,2,2, E_BIAS|E_WB16, 0><<<dim3(D/64, (B*NQ)/64, 1), blk, 0, stream>>>(
      tq_b, Wq_b, bq, nullptr, nullptr, q_b, D, D, D, D, 1, 0,0,0,0,0,0, 1.f);
  //    kv = mtxt @ [Wk;Wv]^T + [bk;bv]  (1024 blocks, 64x128)
  gemm_bf16<64,128,2,2, E_BIAS|E_WB16, 0><<<dim3(2048/128, (B*LT)/64, 1), blk, 0, stream>>>(
      mtxt_b, kvW, bkv, nullptr, nullptr, kv_b, FTXT, FTXT, FTXT, 2048, 1,
      0,0,0,0,0,0, 1.f);

  // 3) vT[b][d][l] = v[b][l][d]
  transpose_u16<<<dim3(D/32, LT/32, B), blk, 0, stream>>>(
      kv_b + 1024, vT_b, LT, D, 2048, (long long)LT * 2048, (long long)D * LT);

  // 4) scores[b,h,q,l] = (q_h . k_h) / 8   (1024 blocks)
  gemm_bf16<128,128,2,2, E_WF32, 0><<<dim3(LT/128, NQ/128, B*H), blk, 0, stream>>>(
      q_b, kv_b, nullptr, nullptr, scores, nullptr, HD, D, 2048, LT, H,
      sQ, HD, (long long)LT * 2048, HD, (long long)H * sSC, sSC, 0.125f);

  // 5) fused softmax + head-mean
  txt_softmax_mean<<<dim3(B*NQ), blk, 0, stream>>>(scores, mtx_m, w_b, out1);

  // 6) ctx = w_h @ v_h  (512 blocks)
  gemm_bf16<64,64,2,2, E_WB16, 0><<<dim3(HD/64, NQ/64, B*H), blk, 0, stream>>>(
      w_b, vT_b, nullptr, nullptr, nullptr, ctx_b, LT, LT, LT, D, H,
      (long long)H * sSC, sSC, (long long)D * LT, (long long)HD * LT, sQ, HD, 1.f);

  // 7) x1p = tgt + ctx @ Wo^T + bo  (512 blocks)
  gemm_bf16<64,64,2,2, E_BIAS|E_RES|E_WF32, 0><<<dim3(D/64, (B*NQ)/64, 1), blk, 0, stream>>>(
      ctx_b, Wo_b, bo, tgt, x1p, nullptr, D, D, D, D, 1, 0,0,0,0,0,0, 1.f);

  // 8) LN1 -> x1 (f32 + bf16)
  ln_kernel<<<dim3(B*NQ), blk, 0, stream>>>(x1p, ln1g, ln1b, x1f, x1_b, 1.f);

  // 9) ff1 = relu(x1 @ W1^T + b1)  (512 blocks)
  gemm_bf16<128,64,2,2, E_BIAS|E_RELU|E_WB16, 0><<<dim3(DFF/64, (B*NQ)/128, 1), blk, 0, stream>>>(
      x1_b, W1_b, b1, nullptr, nullptr, ff1_b, D, D, D, DFF, 1, 0,0,0,0,0,0, 1.f);

  // 10) x2p = x1 + ff1 @ W2^T + b2  (512 blocks)
  gemm_bf16<64,64,2,2, E_BIAS|E_RES|E_WF32, 0><<<dim3(D/64, (B*NQ)/64, 1), blk, 0, stream>>>(
      ff1_b, W2_b, b2, x1f, x2p, nullptr, DFF, DFF, DFF, D, 1, 0,0,0,0,0,0, 1.f);

  // 11) LN2 -> x2s (bf16, /sqrt(D))
  ln_kernel<<<dim3(B*NQ), blk, 0, stream>>>(x2p, ln2g, ln2b, nullptr, x2s_b, 0.03125f);

  // 12) out2 = x2s @ vox^T — B staged directly from f32 vox (1024 blocks)
  gemm_bf16<64,128,2,2, E_WF32, 1><<<dim3(NV/128, NQ/64, B), blk, 0, stream>>>(
      x2s_b, vox, nullptr, nullptr, out2, nullptr, D, D, D, NV, 1,
      sQ, 0, (long long)NV * D, 0, (long long)NQ * NV, 0, 1.f);

  // 13) masked softmax in place; bf16 weights
  vox_softmax<<<dim3(B*NQ), blk, 0, stream>>>(out2, vox_m, wvox_b);

  // 14) out0 partials: split-K=4 over NV; B transpose-staged from f32 vox
  //     (1024 blocks), then reduce
  gemm_bf16<64,128,2,2, E_WF32, 2><<<dim3(D/128, NQ/64, B*4), blk, 0, stream>>>(
      wvox_b, vox, nullptr, nullptr, part, nullptr, NV/4, NV, D, D, 4,
      (long long)NQ * NV, 1024, (long long)NV * D, (long long)1024 * D,
      4 * nd, nd, 1.f);
  splitk_reduce<<<dim3((B * NQ * D) / 1024), blk, 0, stream>>>(part, out0);
}